// Round 1
// 401.044 us; speedup vs baseline: 1.0993x; 1.0993x over previous
//
#include <hip/hip_runtime.h>
#include <math.h>

// Problem constants (fixed by setup_inputs): B=8, C=16, S=64, HID=32
#define SD   64
#define NC   16
#define NHID 32
#define NB   8
#define ALIVE_T 0.1f

// Kernel 1: Sobel(separable, wrap) -> MLP -> y = x + dy*upd
// One wave (64 lanes) owns one (b,d,h) row; w-dim = lane, wrap via __shfl.
// MLP restructured: NO perc[64] array (R1 spilled it to AGPRs at VGPR=56,
// ~2048 extra v_accvgpr_read ops). Each channel's gx/gy/gz/x contributions
// are accumulated straight into hacc[32]; live set ~70 regs.
// __launch_bounds__(256,4): min 4 waves/EU -> VGPR cap 128, no spill.
__global__ __launch_bounds__(256, 4) void nca_step(
    const float* __restrict__ x, const float* __restrict__ rm,
    const float* __restrict__ W1, const float* __restrict__ b1,
    const float* __restrict__ W2, float* __restrict__ y,
    float* __restrict__ alpha)
{
    const int lane = threadIdx.x & 63;                 // w
    const int r    = blockIdx.x * 4 + (threadIdx.x >> 6);
    const int h    = r & 63;
    const int d    = (r >> 6) & 63;
    const int b    = r >> 12;

    const int dm = (d + 63) & 63, dp = (d + 1) & 63;   // wrap in d
    const int hm = (h + 63) & 63, hp = (h + 1) & 63;   // wrap in h
    const int lm = (lane + 63) & 63, lp = (lane + 1) & 63;  // wrap in w

    // 9 row offsets, shared across all channels
    const int o_mm = (dm << 12) + (hm << 6) + lane;
    const int o_m0 = (dm << 12) + (h  << 6) + lane;
    const int o_mp = (dm << 12) + (hp << 6) + lane;
    const int o_0m = (d  << 12) + (hm << 6) + lane;
    const int o_00 = (d  << 12) + (h  << 6) + lane;
    const int o_0p = (d  << 12) + (hp << 6) + lane;
    const int o_pm = (dp << 12) + (hm << 6) + lane;
    const int o_p0 = (dp << 12) + (h  << 6) + lane;
    const int o_pp = (dp << 12) + (hp << 6) + lane;

    float hacc[NHID];
    #pragma unroll
    for (int o = 0; o < NHID; ++o) hacc[o] = b1[o];

    float xv[NC];   // keep center x for the residual add

    #pragma unroll
    for (int c = 0; c < NC; ++c) {
        const float* base = x + (((size_t)(b * NC + c)) << 18);
        float v_mm = base[o_mm], v_m0 = base[o_m0], v_mp = base[o_mp];
        float v_0m = base[o_0m], v_00 = base[o_00], v_0p = base[o_0p];
        float v_pm = base[o_pm], v_p0 = base[o_p0], v_pp = base[o_pp];
        // h-direction partials per d-slice
        float am = v_mm + 2.f * v_m0 + v_mp;
        float a0 = v_0m + 2.f * v_00 + v_0p;
        float ap = v_pm + 2.f * v_p0 + v_pp;
        float gm = v_mp - v_mm;
        float g0 = v_0p - v_0m;
        float gp = v_pp - v_pm;
        // d-direction combine
        float P_hh = am + 2.f * a0 + ap;       // H_d H_h
        float P_hg = gm + 2.f * g0 + gp;       // H_d G_h
        float P_gh = ap - am;                  // G_d H_h
        // w-direction finish via lane shuffles (wrap = &63)
        float gx = __shfl(P_hh, lp, 64) - __shfl(P_hh, lm, 64);              // H H G
        float gy = __shfl(P_hg, lm, 64) + 2.f * P_hg + __shfl(P_hg, lp, 64); // H G H
        float gz = __shfl(P_gh, lm, 64) + 2.f * P_gh + __shfl(P_gh, lp, 64); // G H H
        xv[c] = v_00;
        // accumulate this channel's 4 features into all 32 hidden units;
        // W1 indices are wave-uniform -> s_load scalar operands
        #pragma unroll
        for (int o = 0; o < NHID; ++o) {
            float t = fmaf(W1[(o << 6) + c],          gx,   hacc[o]);
            t       = fmaf(W1[(o << 6) + NC + c],     gy,   t);
            t       = fmaf(W1[(o << 6) + 2 * NC + c], gz,   t);
            hacc[o] = fmaf(W1[(o << 6) + 3 * NC + c], v_00, t);
        }
    }

    // relu + second layer
    float dyv[NC];
    #pragma unroll
    for (int ch = 0; ch < NC; ++ch) dyv[ch] = 0.f;
    #pragma unroll
    for (int o = 0; o < NHID; ++o) {
        float a = fmaxf(hacc[o], 0.f);
        #pragma unroll
        for (int ch = 0; ch < NC; ++ch)
            dyv[ch] = fmaf(W2[(ch << 5) + o], a, dyv[ch]);
    }

    // y = x + dy * floor(rm + 0.25); write y, and alpha = y[:,3]
    const size_t voff = ((size_t)d << 12) + ((size_t)h << 6) + lane;
    #pragma unroll
    for (int ch = 0; ch < NC; ++ch) {
        const size_t idx = (((size_t)(b * NC + ch)) << 18) + voff;
        float upd = floorf(rm[idx] + 0.25f);
        float yv  = fmaf(dyv[ch], upd, xv[ch]);
        y[idx] = yv;
        if (ch == 3) alpha[(((size_t)b) << 18) + voff] = yv;
    }
}

// Kernel 2: 3x3x3 max-pool of alpha (-inf borders, NO wrap), then mask.
// KEY: alive = (pooled > 0.1). alpha ~ N(0,1) (dy is ~1e-3), so
// P(dead) = P(max of 27 normals <= 0.1) = 0.5398^27 ~= 6e-8 -> the mask
// is 1 essentially everywhere and y*=mask is a no-op. nca_step already
// wrote every y element, so we only need to STORE ZEROS where dead:
// no 268 MB y read-modify-write at all. Correct for arbitrary data
// (conditional stores), ~0 stores for this distribution.
__global__ __launch_bounds__(256, 4) void alive_mask(
    const float* __restrict__ alpha, float* __restrict__ y)
{
    const int tid  = blockIdx.x * 256 + threadIdx.x;
    const int lane = threadIdx.x & 63;
    const int wq   = tid & 15;          // which float4 in the row
    const int w4   = wq << 2;
    const int h    = (tid >> 4) & 63;
    const int d    = (tid >> 10) & 63;
    const int b    = tid >> 16;

    const float* ab = alpha + (((size_t)b) << 18);

    float m0 = -INFINITY, m1 = -INFINITY, m2 = -INFINITY, m3 = -INFINITY;
    #pragma unroll
    for (int dz = -1; dz <= 1; ++dz) {
        int dd = d + dz;
        if (dd < 0 || dd > 63) continue;   // -inf border (padding, not wrap)
        #pragma unroll
        for (int hy = -1; hy <= 1; ++hy) {
            int hh = h + hy;
            if (hh < 0 || hh > 63) continue;
            const float4 v = *reinterpret_cast<const float4*>(
                ab + (dd << 12) + (hh << 6) + w4);
            m0 = fmaxf(m0, v.x); m1 = fmaxf(m1, v.y);
            m2 = fmaxf(m2, v.z); m3 = fmaxf(m3, v.w);
        }
    }
    // w-direction: neighbors via lane shuffle; wave lanes 0..15 = one row,
    // row-crossing shuffles are exactly the wq==0 / wq==15 cases -> -inf.
    float left  = __shfl(m3, (lane + 63) & 63, 64);
    float right = __shfl(m0, (lane + 1) & 63, 64);
    if (wq == 0)  left  = -INFINITY;
    if (wq == 15) right = -INFINITY;

    float p0 = fmaxf(left, fmaxf(m0, m1));
    float p1 = fmaxf(m0,   fmaxf(m1, m2));
    float p2 = fmaxf(m1,   fmaxf(m2, m3));
    float p3 = fmaxf(m2,   fmaxf(m3, right));

    const bool d0 = !(p0 > ALIVE_T);
    const bool d1 = !(p1 > ALIVE_T);
    const bool d2 = !(p2 > ALIVE_T);
    const bool d3 = !(p3 > ALIVE_T);

    if (d0 | d1 | d2 | d3) {               // ~never taken; exec-mask skip
        const size_t voff = ((size_t)d << 12) + ((size_t)h << 6) + w4;
        #pragma unroll
        for (int ch = 0; ch < NC; ++ch) {
            float* p = y + (((size_t)(b * NC + ch)) << 18) + voff;
            if (d0) p[0] = 0.f;
            if (d1) p[1] = 0.f;
            if (d2) p[2] = 0.f;
            if (d3) p[3] = 0.f;
        }
    }
}

extern "C" void kernel_launch(void* const* d_in, const int* in_sizes, int n_in,
                              void* d_out, int out_size, void* d_ws, size_t ws_size,
                              hipStream_t stream) {
    const float* x  = (const float*)d_in[0];
    const float* rm = (const float*)d_in[1];
    const float* W1 = (const float*)d_in[2];
    const float* b1 = (const float*)d_in[3];
    const float* W2 = (const float*)d_in[4];
    float* y     = (float*)d_out;
    float* alpha = (float*)d_ws;   // 8 * 64^3 * 4 = 8 MB scratch

    const int rows    = NB * SD * SD;       // 32768 (b,d,h) rows
    const int blocks1 = rows / 4;           // 4 waves (rows) per block
    const int blocks2 = (NB * SD * SD * 16) / 256;  // 4 voxels per thread

    nca_step<<<blocks1, 256, 0, stream>>>(x, rm, W1, b1, W2, y, alpha);
    alive_mask<<<blocks2, 256, 0, stream>>>(alpha, y);
}

// Round 2
// 370.195 us; speedup vs baseline: 1.1909x; 1.0833x over previous
//
#include <hip/hip_runtime.h>
#include <hip/hip_bf16.h>
#include <math.h>

// Problem constants (fixed by setup_inputs): B=8, C=16, S=64, HID=32
#define SD   64
#define NC   16
#define NHID 32
#define NB   8
#define ALIVE_T 0.1f
#define LSTR 160   // LDS bytes per voxel row: 128B feats (+H/dy overlays) + pad
                   // 160 = 40 dwords -> row-to-row bank rotation of 8 (gcd 2),
                   // 16B-aligned so ds_read_b128 works at +16k offsets.

typedef float        f32x4  __attribute__((ext_vector_type(4)));
typedef short        bf16x8 __attribute__((ext_vector_type(8)));
typedef unsigned int u32x2  __attribute__((ext_vector_type(2)));

static __device__ __forceinline__ unsigned short f2bf(float f) {
    return __builtin_bit_cast(unsigned short, __float2bfloat16(f));
}
static __device__ __forceinline__ unsigned pack2(float lo, float hi) {
    return (unsigned)f2bf(lo) | ((unsigned)f2bf(hi) << 16);
}

// Kernel 1: Sobel(separable, wrap) -> MLP (MFMA) -> y = x + dy*upd
// One wave owns one (b,d,h) row; w = lane. The per-voxel MLP across the
// wave's 64 voxels is a GEMM pair:
//   D1^T[32hid x 64vox] = W1[32x64] . perc^T[64feat x 64vox]   (16 MFMA)
//   dy^T[16ch x 64vox]  = W2[16x32] . relu(D1^T)               ( 4 MFMA)
// replacing 2560 scalar fp32 FMAs/thread (the 86%-VALUBusy bottleneck).
// All LDS traffic is wave-private -> no __syncthreads; same-wave DS ops
// execute in order, so feature writes -> frag reads -> H overlay writes
// -> H reads -> dy overlay writes -> dy reads need no explicit sync.
// MFMA layouts used (m89/m91/m92-verified conventions):
//   A-frag: row = lane&15, k = (lane>>4)*8 + j   (k-contiguous b128 load)
//   B-frag: col = lane&15, k = (lane>>4)*8 + j
//   C/D   : col = lane&15, row = (lane>>4)*4 + reg
__global__ __launch_bounds__(256, 4) void nca_step(
    const float* __restrict__ x, const float* __restrict__ rm,
    const float* __restrict__ W1, const float* __restrict__ b1,
    const float* __restrict__ W2, float* __restrict__ y,
    float* __restrict__ alpha)
{
    const int tid  = threadIdx.x;
    const int lane = tid & 63;                 // w (voxel within row)
    const int wid  = tid >> 6;
    const int r    = blockIdx.x * 4 + wid;
    const int h    = r & 63;
    const int d    = (r >> 6) & 63;
    const int b    = r >> 12;

    const int lg = lane >> 4;                  // lane group 0..3 (k-group)
    const int ln = lane & 15;                  // row/col within MFMA tile

    __shared__ __align__(16) unsigned char lds_all[4][64 * LSTR];
    unsigned char* lds   = lds_all[wid];
    unsigned char* myrow = lds + lane * LSTR;

    // ---- hoist weight fragments (fp32 global -> bf16 regs, once/wave) ----
    // GEMM1 A = W1: lane holds W1[hid = ln+16*mt][feat = ks*32 + lg*8 + j]
    bf16x8 a1[2][2];
    #pragma unroll
    for (int mt = 0; mt < 2; ++mt)
      #pragma unroll
      for (int ks = 0; ks < 2; ++ks) {
        const float* wp = W1 + (ln + 16 * mt) * 64 + ks * 32 + lg * 8;
        f32x4 w0 = *(const f32x4*)wp;
        f32x4 w1 = *(const f32x4*)(wp + 4);
        bf16x8 f;
        f[0]=(short)f2bf(w0[0]); f[1]=(short)f2bf(w0[1]);
        f[2]=(short)f2bf(w0[2]); f[3]=(short)f2bf(w0[3]);
        f[4]=(short)f2bf(w1[0]); f[5]=(short)f2bf(w1[1]);
        f[6]=(short)f2bf(w1[2]); f[7]=(short)f2bf(w1[3]);
        a1[mt][ks] = f;
      }
    // GEMM2 A = W2: lane holds W2[ch = ln][hid = lg*8 + j]
    bf16x8 a2;
    {
        const float* wp = W2 + ln * 32 + lg * 8;
        f32x4 w0 = *(const f32x4*)wp;
        f32x4 w1 = *(const f32x4*)(wp + 4);
        a2[0]=(short)f2bf(w0[0]); a2[1]=(short)f2bf(w0[1]);
        a2[2]=(short)f2bf(w0[2]); a2[3]=(short)f2bf(w0[3]);
        a2[4]=(short)f2bf(w1[0]); a2[5]=(short)f2bf(w1[1]);
        a2[6]=(short)f2bf(w1[2]); a2[7]=(short)f2bf(w1[3]);
    }
    // bias: acc1[mt][nt][reg] must init to b1[lg*4 + reg + 16*mt]
    const f32x4 b1lo = *(const f32x4*)(b1 + lg * 4);
    const f32x4 b1hi = *(const f32x4*)(b1 + 16 + lg * 4);

    // ---- Sobel (fp32, unchanged math) + bf16 feature store ----
    const int dm = (d + 63) & 63, dp = (d + 1) & 63;
    const int hm = (h + 63) & 63, hp = (h + 1) & 63;
    const int lm = (lane + 63) & 63, lp = (lane + 1) & 63;

    const int o_mm = (dm << 12) + (hm << 6) + lane;
    const int o_m0 = (dm << 12) + (h  << 6) + lane;
    const int o_mp = (dm << 12) + (hp << 6) + lane;
    const int o_0m = (d  << 12) + (hm << 6) + lane;
    const int o_00 = (d  << 12) + (h  << 6) + lane;
    const int o_0p = (d  << 12) + (hp << 6) + lane;
    const int o_pm = (dp << 12) + (hm << 6) + lane;
    const int o_p0 = (dp << 12) + (h  << 6) + lane;
    const int o_pp = (dp << 12) + (hp << 6) + lane;

    float xv[NC];   // center x stays fp32 for the exact residual add

    // feature index f: 0..15 = gx(ch), 16..31 = gy, 32..47 = gz, 48..63 = x
    // perc[vox][f] bf16 at byte f*2; channels paired so each class write is b32
    #pragma unroll
    for (int c0 = 0; c0 < NC; c0 += 2) {
        float fa[4], fb[4];
        #pragma unroll
        for (int cc = 0; cc < 2; ++cc) {
            const int c = c0 + cc;
            const float* base = x + (((size_t)(b * NC + c)) << 18);
            float v_mm = base[o_mm], v_m0 = base[o_m0], v_mp = base[o_mp];
            float v_0m = base[o_0m], v_00 = base[o_00], v_0p = base[o_0p];
            float v_pm = base[o_pm], v_p0 = base[o_p0], v_pp = base[o_pp];
            float am = v_mm + 2.f * v_m0 + v_mp;
            float a0 = v_0m + 2.f * v_00 + v_0p;
            float ap = v_pm + 2.f * v_p0 + v_pp;
            float gm = v_mp - v_mm;
            float g0 = v_0p - v_0m;
            float gp = v_pp - v_pm;
            float P_hh = am + 2.f * a0 + ap;
            float P_hg = gm + 2.f * g0 + gp;
            float P_gh = ap - am;
            float gx = __shfl(P_hh, lp, 64) - __shfl(P_hh, lm, 64);
            float gy = __shfl(P_hg, lm, 64) + 2.f * P_hg + __shfl(P_hg, lp, 64);
            float gz = __shfl(P_gh, lm, 64) + 2.f * P_gh + __shfl(P_gh, lp, 64);
            float* o = cc ? fb : fa;           // compile-time under unroll
            o[0] = gx; o[1] = gy; o[2] = gz; o[3] = v_00;
            xv[c] = v_00;
        }
        *(unsigned*)(myrow +       2 * c0) = pack2(fa[0], fb[0]);  // gx
        *(unsigned*)(myrow + 32 +  2 * c0) = pack2(fa[1], fb[1]);  // gy
        *(unsigned*)(myrow + 64 +  2 * c0) = pack2(fa[2], fb[2]);  // gz
        *(unsigned*)(myrow + 96 +  2 * c0) = pack2(fa[3], fb[3]);  // x
    }

    // ---- GEMM1: D1^T = W1 . perc^T  (+b1), acc fp32 ----
    f32x4 acc1[2][4];
    #pragma unroll
    for (int nt = 0; nt < 4; ++nt) { acc1[0][nt] = b1lo; acc1[1][nt] = b1hi; }

    #pragma unroll
    for (int ks = 0; ks < 2; ++ks) {
        bf16x8 bp[4];
        #pragma unroll
        for (int nt = 0; nt < 4; ++nt)   // B-frag: col vox = ln+16nt, k = feats
            bp[nt] = *(const bf16x8*)(lds + (ln + 16 * nt) * LSTR + ks * 64 + lg * 16);
        #pragma unroll
        for (int mt = 0; mt < 2; ++mt)
          #pragma unroll
          for (int nt = 0; nt < 4; ++nt)
            acc1[mt][nt] = __builtin_amdgcn_mfma_f32_16x16x32_bf16(
                a1[mt][ks], bp[nt], acc1[mt][nt], 0, 0, 0);
    }

    // ---- relu -> bf16 H[vox][hid] overlay at row bytes [0,64) ----
    // lane's 4 regs of tile (mt,nt) are hid = lg*4+{0..3}+16mt at vox = ln+16nt
    // -> 4 consecutive hid = one 8B contiguous ds_write_b64
    #pragma unroll
    for (int mt = 0; mt < 2; ++mt)
      #pragma unroll
      for (int nt = 0; nt < 4; ++nt) {
        f32x4 v = acc1[mt][nt];
        u32x2 u;
        u[0] = pack2(fmaxf(v[0], 0.f), fmaxf(v[1], 0.f));
        u[1] = pack2(fmaxf(v[2], 0.f), fmaxf(v[3], 0.f));
        *(u32x2*)(lds + (ln + 16 * nt) * LSTR + (lg * 8 + 32 * mt)) = u;
      }

    // ---- GEMM2: dy^T = W2 . H^T ----
    f32x4 acc2[4];
    #pragma unroll
    for (int nt = 0; nt < 4; ++nt) acc2[nt] = (f32x4){0.f, 0.f, 0.f, 0.f};
    #pragma unroll
    for (int nt = 0; nt < 4; ++nt) {
        bf16x8 bh = *(const bf16x8*)(lds + (ln + 16 * nt) * LSTR + lg * 16);
        acc2[nt] = __builtin_amdgcn_mfma_f32_16x16x32_bf16(a2, bh, acc2[nt], 0, 0, 0);
    }

    // ---- dy^T -> f32 DY[vox][ch] overlay at row bytes [64,128) ----
    // lane's 4 regs (ch = lg*4+{0..3}) at vox = ln+16nt -> contiguous b128
    #pragma unroll
    for (int nt = 0; nt < 4; ++nt)
        *(f32x4*)(lds + (ln + 16 * nt) * LSTR + 64 + lg * 16) = acc2[nt];

    // read back in original lane=vox layout -> coalesced epilogue
    float dyv[NC];
    #pragma unroll
    for (int j = 0; j < 4; ++j) {
        f32x4 t = *(const f32x4*)(myrow + 64 + j * 16);
        dyv[4 * j + 0] = t[0]; dyv[4 * j + 1] = t[1];
        dyv[4 * j + 2] = t[2]; dyv[4 * j + 3] = t[3];
    }

    // y = x + dy * floor(rm + 0.25); write y, and alpha = y[:,3]
    const size_t voff = ((size_t)d << 12) + ((size_t)h << 6) + lane;
    #pragma unroll
    for (int ch = 0; ch < NC; ++ch) {
        const size_t idx = (((size_t)(b * NC + ch)) << 18) + voff;
        float upd = floorf(rm[idx] + 0.25f);
        float yv  = fmaf(dyv[ch], upd, xv[ch]);
        y[idx] = yv;
        if (ch == 3) alpha[(((size_t)b) << 18) + voff] = yv;
    }
}

// Kernel 2: 3x3x3 max-pool of alpha (-inf borders, NO wrap), then mask.
// alive = (pooled > 0.1); P(dead) ~ 6e-8 for this data -> store zeros only
// where dead (conditional, exec-masked); no y read-modify-write.
__global__ __launch_bounds__(256, 4) void alive_mask(
    const float* __restrict__ alpha, float* __restrict__ y)
{
    const int tid  = blockIdx.x * 256 + threadIdx.x;
    const int lane = threadIdx.x & 63;
    const int wq   = tid & 15;          // which float4 in the row
    const int w4   = wq << 2;
    const int h    = (tid >> 4) & 63;
    const int d    = (tid >> 10) & 63;
    const int b    = tid >> 16;

    const float* ab = alpha + (((size_t)b) << 18);

    float m0 = -INFINITY, m1 = -INFINITY, m2 = -INFINITY, m3 = -INFINITY;
    #pragma unroll
    for (int dz = -1; dz <= 1; ++dz) {
        int dd = d + dz;
        if (dd < 0 || dd > 63) continue;   // -inf border (padding, not wrap)
        #pragma unroll
        for (int hy = -1; hy <= 1; ++hy) {
            int hh = h + hy;
            if (hh < 0 || hh > 63) continue;
            const float4 v = *reinterpret_cast<const float4*>(
                ab + (dd << 12) + (hh << 6) + w4);
            m0 = fmaxf(m0, v.x); m1 = fmaxf(m1, v.y);
            m2 = fmaxf(m2, v.z); m3 = fmaxf(m3, v.w);
        }
    }
    float left  = __shfl(m3, (lane + 63) & 63, 64);
    float right = __shfl(m0, (lane + 1) & 63, 64);
    if (wq == 0)  left  = -INFINITY;
    if (wq == 15) right = -INFINITY;

    float p0 = fmaxf(left, fmaxf(m0, m1));
    float p1 = fmaxf(m0,   fmaxf(m1, m2));
    float p2 = fmaxf(m1,   fmaxf(m2, m3));
    float p3 = fmaxf(m2,   fmaxf(m3, right));

    const bool d0 = !(p0 > ALIVE_T);
    const bool d1 = !(p1 > ALIVE_T);
    const bool d2 = !(p2 > ALIVE_T);
    const bool d3 = !(p3 > ALIVE_T);

    if (d0 | d1 | d2 | d3) {               // ~never taken; exec-mask skip
        const size_t voff = ((size_t)d << 12) + ((size_t)h << 6) + w4;
        #pragma unroll
        for (int ch = 0; ch < NC; ++ch) {
            float* p = y + (((size_t)(b * NC + ch)) << 18) + voff;
            if (d0) p[0] = 0.f;
            if (d1) p[1] = 0.f;
            if (d2) p[2] = 0.f;
            if (d3) p[3] = 0.f;
        }
    }
}

extern "C" void kernel_launch(void* const* d_in, const int* in_sizes, int n_in,
                              void* d_out, int out_size, void* d_ws, size_t ws_size,
                              hipStream_t stream) {
    const float* x  = (const float*)d_in[0];
    const float* rm = (const float*)d_in[1];
    const float* W1 = (const float*)d_in[2];
    const float* b1 = (const float*)d_in[3];
    const float* W2 = (const float*)d_in[4];
    float* y     = (float*)d_out;
    float* alpha = (float*)d_ws;   // 8 * 64^3 * 4 = 8 MB scratch

    const int rows    = NB * SD * SD;       // 32768 (b,d,h) rows
    const int blocks1 = rows / 4;           // 4 waves (rows) per block
    const int blocks2 = (NB * SD * SD * 16) / 256;  // 4 voxels per thread

    nca_step<<<blocks1, 256, 0, stream>>>(x, rm, W1, b1, W2, y, alpha);
    alive_mask<<<blocks2, 256, 0, stream>>>(alpha, y);
}